// Round 6
// baseline (714.424 us; speedup 1.0000x reference)
//
#include <hip/hip_runtime.h>

// GraphProbeFeatures: B=128, N=4096, H=128, D_OUT=3, P=128. fp32 I/O.
// Round 6: revert pw staging to normal vector loads (round-5's
// global_load_lds proved non-caching on gfx950: FETCH 1.06GB / WRITE 608MB
// = DMA streaming HBM; round-4 normal loads hit L2 at 96%+). Keep 4-way
// n-split (grid 512, 2 blocks/CU), 3-barrier iteration, z3 algebraic fold,
// register-resident W1, k_ln partial-reduce + LayerNorm.
// ws: pwT 4MB + xbuf 32KB + zp fp32 [split][128][261][128] (68.5MB @ split=4).

typedef unsigned short u16;
typedef __attribute__((ext_vector_type(8))) short short8;
typedef __attribute__((ext_vector_type(4))) short short4v;
typedef __attribute__((ext_vector_type(4))) float f32x4;

#define DEV __device__ __forceinline__

DEV float b2f(u16 h){ return __uint_as_float(((unsigned)h) << 16); }
DEV u16 f2b(float f){
  unsigned u = __float_as_uint(f);
  return (u16)((u + 0x7FFFu + ((u >> 16) & 1u)) >> 16);  // RNE
}
DEV float sin_fast(float x){
  float r = x * 0.15915494309189535f;   // radians -> revolutions
  r = r - rintf(r);                     // [-0.5, 0.5]
#if __has_builtin(__builtin_amdgcn_sinf)
  return __builtin_amdgcn_sinf(r);
#else
  return __sinf(r * 6.283185307179586f);
#endif
}
template<int C> DEV float dpp_add(float x){
  int yi = __builtin_amdgcn_update_dpp(0, __float_as_int(x), C, 0xF, 0xF, true);
  return x + __int_as_float(yi);
}
DEV float sum16(float x){                // total over the 16-lane DPP row
  x = dpp_add<0x128>(x); x = dpp_add<0x124>(x);
  x = dpp_add<0x122>(x); x = dpp_add<0x121>(x);
  return x;
}

DEV int is_bf16_fmt(const void* lng){ return *(const unsigned*)lng == 0x3F803F80u; }
struct In {
  const float* f; const u16* h; int bf;
  DEV In(const void* p, int b_) : f((const float*)p), h((const u16*)p), bf(b_) {}
  DEV float at(size_t i) const { return bf ? b2f(h[i]) : f[i]; }
};

// ---------- k_prep: pw -> pwT bf16 [4][128][4096]; block 256: xbuf fp32 ------
__global__ __launch_bounds__(256) void k_prep(const void* pwv, const void* inpv,
                                              const void* lngv,
                                              u16* __restrict__ pwT,
                                              float* __restrict__ xbuf){
  const int bf = is_bf16_fmt(lngv);
  const int t = threadIdx.x;
  if (blockIdx.x == 256){
    In inp(inpv, bf);
    for (int i = t; i < 8192; i += 256) xbuf[i] = inp.at(i);
    return;
  }
  In pw(pwv, bf);
  __shared__ u16 tile[64 * 129];
  const int layer = blockIdx.x >> 6;
  const int n0 = (blockIdx.x & 63) * 64;
  const size_t base = ((size_t)layer * 4096 + n0) * 128;
#pragma unroll
  for (int k = 0; k < 32; k++){
    int idx = k * 256 + t, n = idx >> 7, p = idx & 127;
    tile[n * 129 + p] = f2b(pw.at(base + (size_t)n * 128 + p));
  }
  __syncthreads();
  u16* dst = pwT + (size_t)layer * 128 * 4096 + n0;
#pragma unroll
  for (int k = 0; k < 32; k++){
    int idx = k * 256 + t, p = idx >> 6, n = idx & 63;
    dst[(size_t)p * 4096 + n] = tile[n * 129 + p];
  }
}

// ---------- k_main: fused SIREN + projections ----------
// grid = 128*split, b = blockIdx&127, sseg = blockIdx>>7, TS = 128/split tiles.
// PARTIAL: write fp32 partial z-rows (no pb) to outp = zp[sseg][b][261][128].
// !PARTIAL: in-kernel LayerNorm + emit (split==1 fallback).
#define S_NK 136   // [n][h] row stride u16
#define S_T  40    // [x][n] row stride u16

template<bool PARTIAL>
__global__ __launch_bounds__(512, 4)
void k_main(const void* w0v, const void* w1v, const void* w2v,
            const void* b0v, const void* b1v, const void* b2v,
            const void* pbv, const void* lgv, const void* lbv,
            const u16* __restrict__ pwTg, const float* __restrict__ xbuf,
            float* __restrict__ outp, int TS){
  __shared__ __align__(16) u16 spw[4][128 * S_T]; // 4 pw tiles [p][n], padded
  __shared__ __align__(16) u16 sh1nk[32 * S_NK];  // h1 [n][h]
  __shared__ __align__(16) u16 sh1T[128 * S_T];   // h1^T [h][n]
  __shared__ __align__(16) u16 sh2T[128 * S_T];   // h2^T [h][n]
  __shared__ __align__(16) u16 sxT[16 * S_T];     // x^T [d][n], rows 2..15 zero
  __shared__ float sW2[512];                      // [128][4], col 3 zero
  __shared__ float sb2[4];
  __shared__ float sPB[512], sG[512], sBB[512];

  // epilogue aliases (FULL path only, after final barrier)
  float* sP1 = (float*)sh1nk;
  float* sP2 = (float*)sh1T;
  float* sM  = (float*)sh2T;
  float* sI  = (float*)sh2T + 512;

  const int bf = is_bf16_fmt(lgv);
  In w0(w0v, bf), w1(w1v, bf), w2(w2v, bf), b0(b0v, bf), b1(b1v, bf),
     b2(b2v, bf), pb(pbv, bf), lg(lgv, bf), lb(lbv, bf);

  const int t = threadIdx.x;
  const int b = blockIdx.x & 127, sseg = blockIdx.x >> 7;
  const int lane = t & 63, wave = t >> 6, quad = lane >> 4, r16 = lane & 15;
  const int oo = wave * 16 + r16;

  // ---- one-time staging ----
  if (t >= 256 && t < 384){
    int i = t - 256;
    sW2[i * 4 + 0] = w2.at(((size_t)b * 128 + i) * 3 + 0);
    sW2[i * 4 + 1] = w2.at(((size_t)b * 128 + i) * 3 + 1);
    sW2[i * 4 + 2] = w2.at(((size_t)b * 128 + i) * 3 + 2);
    sW2[i * 4 + 3] = 0.f;
  }
  if (t < 4) sb2[t] = (t < 3) ? b2.at(b * 3 + t) : 0.f;
  sPB[t] = pb.at(t); sG[t] = lg.at(t); sBB[t] = lb.at(t);
  for (int k = t; k < 16 * S_T; k += 512) sxT[k] = 0;

  // pass-1: thread computes h = p1hb..+7 for n = p1n
  const int p1n = t >> 4, p1hb = (t & 15) * 8;
  float w00[8], w01[8], b00[8];
#pragma unroll
  for (int j = 0; j < 8; j++){
    w00[j] = w0.at((size_t)b * 256 + p1hb + j);
    w01[j] = w0.at((size_t)b * 256 + 128 + p1hb + j);
    b00[j] = b0.at((size_t)b * 128 + p1hb + j);
  }
  // pass-2: thread computes h = p2h for n = p2nb..+7
  const int p2h = t & 127, p2nb = (t >> 7) * 8;
  const float q00 = w0.at((size_t)b * 256 + p2h);
  const float q01 = w0.at((size_t)b * 256 + 128 + p2h);
  const float qb0 = b0.at((size_t)b * 128 + p2h);
  const float bias1 = b1.at((size_t)b * 128 + oo);

  // W1^T B-fragments (register-resident)
  short8 w1f[4];
#pragma unroll
  for (int ks = 0; ks < 4; ks++){
#pragma unroll
    for (int j = 0; j < 8; j++)
      w1f[ks][j] = (short)f2b(w1.at((size_t)b * 16384 +
                                    (size_t)(ks * 32 + quad * 8 + j) * 128 + oo));
  }
  // ones-row A fragment for S3 = sum_n pw3[n][p]
  short8 a1s = {0,0,0,0,0,0,0,0};
  if (r16 == 0){
#pragma unroll
    for (int j = 0; j < 8; j++) a1s[j] = (short)0x3F80;
  }

  // pw staging: thread stages row pwrow, chunk pwc of each layer tile.
  const int pwrow = t >> 2, pwc = t & 3;
  const u16* pwsrc = pwTg + (size_t)pwrow * 4096 + pwc * 8;  // + L*524288 + n0
  const int pwdofs = pwrow * S_T + pwc * 8;
  // B-frag read offset: row oo, chunk quad
  const int bofs = oo * S_T + quad * 8;

  const f32x4 zz = {0.f,0.f,0.f,0.f};
  f32x4 az1[8], az2[8], ay[8], az0 = zz, az3 = zz;
#pragma unroll
  for (int i = 0; i < 8; i++){ az1[i] = zz; az2[i] = zz; ay[i] = zz; }

  __syncthreads();

  for (int nt = 0; nt < TS; nt++){
    const int n0 = (sseg * TS + nt) * 32;

    // ---- Phase A: issue pw loads (VGPR), compute x + h1, ds_write pw ----
    short8 pwv[4];
#pragma unroll
    for (int L = 0; L < 4; L++)
      pwv[L] = *(const short8*)(pwsrc + (size_t)L * 524288 + n0);
    if (t < 64){
      int n = t >> 1, c = t & 1;
      sxT[c * S_T + n] = f2b(xbuf[(size_t)(n0 + n) * 2 + c]);
    }
    {
      float2 xv = *(const float2*)(xbuf + (size_t)(n0 + p1n) * 2);
      short8 v;
#pragma unroll
      for (int j = 0; j < 8; j++)
        v[j] = (short)f2b(sin_fast(30.f * fmaf(xv.y, w01[j], fmaf(xv.x, w00[j], b00[j]))));
      *(short8*)&sh1nk[p1n * S_NK + p1hb] = v;
    }
    {
      short8 v;
#pragma unroll
      for (int j = 0; j < 8; j++){
        float2 xv = *(const float2*)(xbuf + (size_t)(n0 + p2nb + j) * 2);
        v[j] = (short)f2b(sin_fast(30.f * fmaf(xv.y, q01, fmaf(xv.x, q00, qb0))));
      }
      *(short8*)&sh1T[p2h * S_T + p2nb] = v;
    }
#pragma unroll
    for (int L = 0; L < 4; L++)
      *(short8*)&spw[L][pwdofs] = pwv[L];
    __syncthreads();

    // ---- Phase B: h2 GEMM + z0 + z1 + S3 + h2 epilogue -> sh2T ----
    f32x4 h0 = zz, h1a = zz;
#pragma unroll
    for (int ks = 0; ks < 4; ks++){
      h0  = __builtin_amdgcn_mfma_f32_16x16x32_bf16(
              *(short8*)&sh1nk[r16 * S_NK + ks * 32 + quad * 8], w1f[ks], h0, 0, 0, 0);
      h1a = __builtin_amdgcn_mfma_f32_16x16x32_bf16(
              *(short8*)&sh1nk[(16 + r16) * S_NK + ks * 32 + quad * 8], w1f[ks], h1a, 0, 0, 0);
    }
    az0 = __builtin_amdgcn_mfma_f32_16x16x32_bf16(
            *(short8*)&sxT[r16 * S_T + quad * 8], *(short8*)&spw[0][bofs], az0, 0, 0, 0);
#pragma unroll
    for (int mb = 0; mb < 8; mb++)
      az1[mb] = __builtin_amdgcn_mfma_f32_16x16x32_bf16(
                  *(short8*)&sh1T[(mb * 16 + r16) * S_T + quad * 8],
                  *(short8*)&spw[1][bofs], az1[mb], 0, 0, 0);
    az3 = __builtin_amdgcn_mfma_f32_16x16x32_bf16(a1s, *(short8*)&spw[3][bofs], az3, 0, 0, 0);
    {
      short4v v;
#pragma unroll
      for (int r = 0; r < 4; r++) v[r] = (short)f2b(sin_fast(30.f * (h0[r] + bias1)));
      *(short4v*)&sh2T[oo * S_T + quad * 4] = v;
#pragma unroll
      for (int r = 0; r < 4; r++) v[r] = (short)f2b(sin_fast(30.f * (h1a[r] + bias1)));
      *(short4v*)&sh2T[oo * S_T + 16 + quad * 4] = v;
    }
    __syncthreads();

    // ---- Phase C: z2 + y (read sh2T, spw[2], spw[3]) ----
#pragma unroll
    for (int mb = 0; mb < 8; mb++){
      short8 a = *(short8*)&sh2T[(mb * 16 + r16) * S_T + quad * 8];
      az2[mb] = __builtin_amdgcn_mfma_f32_16x16x32_bf16(a, *(short8*)&spw[2][bofs], az2[mb], 0, 0, 0);
      ay[mb]  = __builtin_amdgcn_mfma_f32_16x16x32_bf16(a, *(short8*)&spw[3][bofs], ay[mb], 0, 0, 0);
    }
    __syncthreads();   // protect sh1*/sxT/sh2T/spw for next iteration
  }

  // ---- z3 fold (linear in partials): z3 = W2^T.y + b2*S3 ----
  const int p = oo;
  float S3 = (quad == 0) ? az3[0] : 0.f;
  S3 += __shfl_xor(S3, 16, 64); S3 += __shfl_xor(S3, 32, 64);
  float z3v[3];
#pragma unroll
  for (int d = 0; d < 3; d++){
    float a = 0.f;
#pragma unroll
    for (int mb = 0; mb < 8; mb++)
#pragma unroll
      for (int r = 0; r < 4; r++)
        a = fmaf(sW2[(mb * 16 + quad * 4 + r) * 4 + d], ay[mb][r], a);
    a += __shfl_xor(a, 16, 64); a += __shfl_xor(a, 32, 64);
    z3v[d] = a + sb2[d] * S3;
  }

  if (PARTIAL){
    float* zp = outp + ((size_t)(sseg * 128 + b)) * 261 * 128;
    if (quad == 0){
#pragma unroll
      for (int r = 0; r < 2; r++) zp[(size_t)r * 128 + p] = az0[r];
#pragma unroll
      for (int d = 0; d < 3; d++) zp[(size_t)(258 + d) * 128 + p] = z3v[d];
    }
#pragma unroll
    for (int mb = 0; mb < 8; mb++)
#pragma unroll
      for (int r = 0; r < 4; r++){
        int drow = mb * 16 + quad * 4 + r;
        zp[(size_t)(2 + drow) * 128 + p]   = az1[mb][r];
        zp[(size_t)(130 + drow) * 128 + p] = az2[mb][r];
      }
    return;
  }

  // ---- FULL path: LN stats + emit ----
  const float pb0v = sPB[p],       pb1v = sPB[128 + p];
  const float pb2v = sPB[256 + p], pb3v = sPB[384 + p];

  auto rowsum = [&](float v, int row, bool wr){
    float s1 = sum16(v), s2 = sum16(v * v);
    if (wr && r16 == 0){ sP1[row * 8 + wave] = s1; sP2[row * 8 + wave] = s2; }
  };
#pragma unroll
  for (int r = 0; r < 2; r++) rowsum(az0[r] + pb0v, r, quad == 0);
#pragma unroll
  for (int mb = 0; mb < 8; mb++)
#pragma unroll
    for (int r = 0; r < 4; r++)
      rowsum(az1[mb][r] + pb1v, 2 + mb * 16 + quad * 4 + r, true);
#pragma unroll
  for (int mb = 0; mb < 8; mb++)
#pragma unroll
    for (int r = 0; r < 4; r++)
      rowsum(az2[mb][r] + pb2v, 130 + mb * 16 + quad * 4 + r, true);
#pragma unroll
  for (int d = 0; d < 3; d++) rowsum(z3v[d] + pb3v, 258 + d, quad == 0);
  __syncthreads();

  if (t < 261){
    float s1 = 0.f, s2 = 0.f;
#pragma unroll
    for (int w = 0; w < 8; w++){ s1 += sP1[t * 8 + w]; s2 += sP2[t * 8 + w]; }
    float m = s1 * (1.f / 128.f);
    float var = fmaf(-m, m, s2 * (1.f / 128.f));
    sM[t] = m;
    sI[t] = rsqrtf(fmaxf(var, 0.f) + 1e-5f);
  }
  __syncthreads();

  const size_t ob = (size_t)b * 261 * 128;
  auto emit = [&](float v, int row, int grp){
    outp[ob + (size_t)row * 128 + p] =
      (v - sM[row]) * sI[row] * sG[grp * 128 + p] + sBB[grp * 128 + p];
  };
  if (quad == 0){
#pragma unroll
    for (int r = 0; r < 2; r++) emit(az0[r] + pb0v, r, 0);
#pragma unroll
    for (int d = 0; d < 3; d++) emit(z3v[d] + pb3v, 258 + d, 3);
  }
#pragma unroll
  for (int mb = 0; mb < 8; mb++)
#pragma unroll
    for (int r = 0; r < 4; r++)
      emit(az1[mb][r] + pb1v, 2 + mb * 16 + quad * 4 + r, 1);
#pragma unroll
  for (int mb = 0; mb < 8; mb++)
#pragma unroll
    for (int r = 0; r < 4; r++)
      emit(az2[mb][r] + pb2v, 130 + mb * 16 + quad * 4 + r, 2);
}

// ---------- k_ln: reduce split partials + pb + LayerNorm -> fp32 out ----------
__global__ __launch_bounds__(256)
void k_ln(const float* __restrict__ zp, const void* pbv, const void* lgv,
          const void* lbv, float* __restrict__ out, int split){
  const int bf = is_bf16_fmt(lgv);
  In pb(pbv, bf), lg(lgv, bf), lb(lbv, bf);
  const int lane = threadIdx.x & 63;
  const int row = blockIdx.x * 4 + (threadIdx.x >> 6);   // < 33408
  const int b = row / 261, d = row % 261;
  const int grp = (d < 2) ? 0 : (d < 130) ? 1 : (d < 258) ? 2 : 3;
  const int p0 = lane * 2;
  float v0 = pb.at(grp * 128 + p0), v1 = pb.at(grp * 128 + p0 + 1);
  for (int s2 = 0; s2 < split; s2++){
    const float* zr = zp + ((size_t)(s2 * 128 + b) * 261 + d) * 128;
    v0 += zr[p0]; v1 += zr[p0 + 1];
  }
  float s1 = v0 + v1, s2s = v0 * v0 + v1 * v1;
#pragma unroll
  for (int o = 1; o < 64; o <<= 1){
    s1 += __shfl_xor(s1, o, 64);
    s2s += __shfl_xor(s2s, o, 64);
  }
  float m = s1 * (1.f / 128.f);
  float var = fmaf(-m, m, s2s * (1.f / 128.f));
  float inv = rsqrtf(fmaxf(var, 0.f) + 1e-5f);
  float2 o2;
  o2.x = (v0 - m) * inv * lg.at(grp * 128 + p0)     + lb.at(grp * 128 + p0);
  o2.y = (v1 - m) * inv * lg.at(grp * 128 + p0 + 1) + lb.at(grp * 128 + p0 + 1);
  *(float2*)(out + (size_t)row * 128 + p0) = o2;
}

extern "C" void kernel_launch(void* const* d_in, const int* in_sizes, int n_in,
                              void* d_out, int out_size, void* d_ws, size_t ws_size,
                              hipStream_t stream){
  const void* w0  = d_in[0];
  const void* w1  = d_in[1];
  const void* w2  = d_in[2];
  const void* b0  = d_in[3];
  const void* b1  = d_in[4];
  const void* b2  = d_in[5];
  const void* inp = d_in[6];
  const void* pw  = d_in[7];
  const void* pb  = d_in[8];
  const void* lng = d_in[9];
  const void* lnb = d_in[10];
  float* out = (float*)d_out;

  u16* pwT    = (u16*)d_ws;                                         // 4 MB
  float* xbuf = (float*)((char*)d_ws + (size_t)4 * 128 * 4096 * 2); // 32 KB
  const size_t zoff = (size_t)4 * 128 * 4096 * 2 + 8192 * 4;
  float* zp = (float*)((char*)d_ws + zoff);
  const size_t seg = (size_t)128 * 261 * 128 * 4;                   // 17.1 MB

  int split = 1;
  if (ws_size >= zoff + 4 * seg) split = 4;
  else if (ws_size >= zoff + 2 * seg) split = 2;

  k_prep<<<257, 256, 0, stream>>>(pw, inp, lng, pwT, xbuf);
  if (split > 1){
    k_main<true><<<128 * split, 512, 0, stream>>>(w0, w1, w2, b0, b1, b2,
        pb, lng, lnb, pwT, xbuf, zp, 128 / split);
    k_ln<<<(128 * 261) / 4, 256, 0, stream>>>(zp, pb, lng, lnb, out, split);
  } else {
    k_main<false><<<128, 512, 0, stream>>>(w0, w1, w2, b0, b1, b2,
        pb, lng, lnb, pwT, xbuf, out, 128);
  }
}

// Round 7
// 251.816 us; speedup vs baseline: 2.8371x; 2.8371x over previous
//
#include <hip/hip_runtime.h>

// GraphProbeFeatures: B=128, N=4096, H=128, D_OUT=3, P=128. fp32 I/O.
// Round 7: rounds 5/6 regressed because __launch_bounds__(512,4) capped the
// unified VGPR/AGPR budget at 128 < the ~160 the kernel needs (96 acc regs) ->
// accumulator spill to scratch -> 2 GB of HBM spill traffic (VGPR_Count=64
// was the tell). Fix: (512,2) = 256-reg budget (round 4: 124 regs, no spill),
// split=2 -> grid 256 = 1 block/CU full chip, and register-prefetch of next
// iteration's pw tiles (+x) issued right after phase-A barrier so global->L2
// latency overlaps phases B+C (no co-resident block to rely on).
// ws: pwT 4MB + xbuf 32KB + zp fp32 [2][128][261][128] (34.2MB).

typedef unsigned short u16;
typedef __attribute__((ext_vector_type(8))) short short8;
typedef __attribute__((ext_vector_type(4))) short short4v;
typedef __attribute__((ext_vector_type(4))) float f32x4;
typedef __attribute__((ext_vector_type(4))) float float4v;

#define DEV __device__ __forceinline__

DEV float b2f(u16 h){ return __uint_as_float(((unsigned)h) << 16); }
DEV u16 f2b(float f){
  unsigned u = __float_as_uint(f);
  return (u16)((u + 0x7FFFu + ((u >> 16) & 1u)) >> 16);  // RNE
}
DEV float sin_fast(float x){
  float r = x * 0.15915494309189535f;   // radians -> revolutions
  r = r - rintf(r);                     // [-0.5, 0.5]
#if __has_builtin(__builtin_amdgcn_sinf)
  return __builtin_amdgcn_sinf(r);
#else
  return __sinf(r * 6.283185307179586f);
#endif
}
template<int C> DEV float dpp_add(float x){
  int yi = __builtin_amdgcn_update_dpp(0, __float_as_int(x), C, 0xF, 0xF, true);
  return x + __int_as_float(yi);
}
DEV float sum16(float x){                // total over the 16-lane DPP row
  x = dpp_add<0x128>(x); x = dpp_add<0x124>(x);
  x = dpp_add<0x122>(x); x = dpp_add<0x121>(x);
  return x;
}

DEV int is_bf16_fmt(const void* lng){ return *(const unsigned*)lng == 0x3F803F80u; }
struct In {
  const float* f; const u16* h; int bf;
  DEV In(const void* p, int b_) : f((const float*)p), h((const u16*)p), bf(b_) {}
  DEV float at(size_t i) const { return bf ? b2f(h[i]) : f[i]; }
};

// ---------- k_prep: pw -> pwT bf16 [4][128][4096]; block 256: xbuf fp32 ------
__global__ __launch_bounds__(256) void k_prep(const void* pwv, const void* inpv,
                                              const void* lngv,
                                              u16* __restrict__ pwT,
                                              float* __restrict__ xbuf){
  const int bf = is_bf16_fmt(lngv);
  const int t = threadIdx.x;
  if (blockIdx.x == 256){
    In inp(inpv, bf);
    for (int i = t; i < 8192; i += 256) xbuf[i] = inp.at(i);
    return;
  }
  In pw(pwv, bf);
  __shared__ u16 tile[64 * 129];
  const int layer = blockIdx.x >> 6;
  const int n0 = (blockIdx.x & 63) * 64;
  const size_t base = ((size_t)layer * 4096 + n0) * 128;
#pragma unroll
  for (int k = 0; k < 32; k++){
    int idx = k * 256 + t, n = idx >> 7, p = idx & 127;
    tile[n * 129 + p] = f2b(pw.at(base + (size_t)n * 128 + p));
  }
  __syncthreads();
  u16* dst = pwT + (size_t)layer * 128 * 4096 + n0;
#pragma unroll
  for (int k = 0; k < 32; k++){
    int idx = k * 256 + t, p = idx >> 6, n = idx & 63;
    dst[(size_t)p * 4096 + n] = tile[n * 129 + p];
  }
}

// ---------- k_main: fused SIREN + projections ----------
#define S_NK 136   // [n][h] row stride u16
#define S_T  40    // [x][n] row stride u16

template<bool PARTIAL>
__global__ __launch_bounds__(512, 2)
void k_main(const void* w0v, const void* w1v, const void* w2v,
            const void* b0v, const void* b1v, const void* b2v,
            const void* pbv, const void* lgv, const void* lbv,
            const u16* __restrict__ pwTg, const float* __restrict__ xbuf,
            float* __restrict__ outp, int TS){
  __shared__ __align__(16) u16 spw[4][128 * S_T]; // 4 pw tiles [p][n], padded
  __shared__ __align__(16) u16 sh1nk[32 * S_NK];  // h1 [n][h]
  __shared__ __align__(16) u16 sh1T[128 * S_T];   // h1^T [h][n]
  __shared__ __align__(16) u16 sh2T[128 * S_T];   // h2^T [h][n]
  __shared__ __align__(16) u16 sxT[16 * S_T];     // x^T [d][n], rows 2..15 zero
  __shared__ float sW2[512];                      // [128][4], col 3 zero
  __shared__ float sb2[4];
  __shared__ float sPB[512], sG[512], sBB[512];

  // epilogue aliases (FULL path only, after final barrier)
  float* sP1 = (float*)sh1nk;
  float* sP2 = (float*)sh1T;
  float* sM  = (float*)sh2T;
  float* sI  = (float*)sh2T + 512;

  const int bf = is_bf16_fmt(lgv);
  In w0(w0v, bf), w1(w1v, bf), w2(w2v, bf), b0(b0v, bf), b1(b1v, bf),
     b2(b2v, bf), pb(pbv, bf), lg(lgv, bf), lb(lbv, bf);

  const int t = threadIdx.x;
  const int b = blockIdx.x & 127, sseg = blockIdx.x >> 7;
  const int lane = t & 63, wave = t >> 6, quad = lane >> 4, r16 = lane & 15;
  const int oo = wave * 16 + r16;

  // ---- one-time staging ----
  if (t >= 256 && t < 384){
    int i = t - 256;
    sW2[i * 4 + 0] = w2.at(((size_t)b * 128 + i) * 3 + 0);
    sW2[i * 4 + 1] = w2.at(((size_t)b * 128 + i) * 3 + 1);
    sW2[i * 4 + 2] = w2.at(((size_t)b * 128 + i) * 3 + 2);
    sW2[i * 4 + 3] = 0.f;
  }
  if (t < 4) sb2[t] = (t < 3) ? b2.at(b * 3 + t) : 0.f;
  sPB[t] = pb.at(t); sG[t] = lg.at(t); sBB[t] = lb.at(t);
  for (int k = t; k < 16 * S_T; k += 512) sxT[k] = 0;

  // pass-1: thread computes h = p1hb..+7 for n = p1n
  const int p1n = t >> 4, p1hb = (t & 15) * 8;
  float w00[8], w01[8], b00[8];
#pragma unroll
  for (int j = 0; j < 8; j++){
    w00[j] = w0.at((size_t)b * 256 + p1hb + j);
    w01[j] = w0.at((size_t)b * 256 + 128 + p1hb + j);
    b00[j] = b0.at((size_t)b * 128 + p1hb + j);
  }
  // pass-2: thread computes h = p2h for n = p2nb..+7 (16 contiguous floats)
  const int p2h = t & 127, p2nb = (t >> 7) * 8;
  const float q00 = w0.at((size_t)b * 256 + p2h);
  const float q01 = w0.at((size_t)b * 256 + 128 + p2h);
  const float qb0 = b0.at((size_t)b * 128 + p2h);
  const float bias1 = b1.at((size_t)b * 128 + oo);

  // W1^T B-fragments (register-resident)
  short8 w1f[4];
#pragma unroll
  for (int ks = 0; ks < 4; ks++){
#pragma unroll
    for (int j = 0; j < 8; j++)
      w1f[ks][j] = (short)f2b(w1.at((size_t)b * 16384 +
                                    (size_t)(ks * 32 + quad * 8 + j) * 128 + oo));
  }
  // ones-row A fragment for S3 = sum_n pw3[n][p]
  short8 a1s = {0,0,0,0,0,0,0,0};
  if (r16 == 0){
#pragma unroll
    for (int j = 0; j < 8; j++) a1s[j] = (short)0x3F80;
  }

  // pw staging: thread stages row pwrow, chunk pwc of each layer tile
  const int pwrow = t >> 2, pwc = t & 3;
  const u16* pwsrc = pwTg + (size_t)pwrow * 4096 + pwc * 8;  // + L*524288 + n0
  const int pwdofs = pwrow * S_T + pwc * 8;
  const int bofs = oo * S_T + quad * 8;    // B-frag read offset

  const f32x4 zz = {0.f,0.f,0.f,0.f};
  f32x4 az1[8], az2[8], ay[8], az0 = zz, az3 = zz;
#pragma unroll
  for (int i = 0; i < 8; i++){ az1[i] = zz; az2[i] = zz; ay[i] = zz; }

  // ---- prologue prefetch for nt = 0 ----
  const int n0first = sseg * TS * 32;
  short8 pwv[4];
#pragma unroll
  for (int L = 0; L < 4; L++)
    pwv[L] = *(const short8*)(pwsrc + (size_t)L * 524288 + n0first);
  float2 xp1 = *(const float2*)(xbuf + (size_t)(n0first + p1n) * 2);

  __syncthreads();

  for (int nt = 0; nt < TS; nt++){
    const int n0 = (sseg * TS + nt) * 32;

    // ---- Phase A: LDS-write prefetched pw, compute h1 (both layouts) ----
    // p2 x loads (fresh; xbuf is L2-resident, latency covered by p1 sins)
    float4v xq[4];
#pragma unroll
    for (int q = 0; q < 4; q++)
      xq[q] = *(const float4v*)(xbuf + (size_t)(n0 + p2nb) * 2 + q * 4);
#pragma unroll
    for (int L = 0; L < 4; L++)
      *(short8*)&spw[L][pwdofs] = pwv[L];
    if ((t & 15) == 0){            // x^T staging from p1 regs
      sxT[p1n] = f2b(xp1.x);
      sxT[S_T + p1n] = f2b(xp1.y);
    }
    {
      short8 v;
#pragma unroll
      for (int j = 0; j < 8; j++)
        v[j] = (short)f2b(sin_fast(30.f * fmaf(xp1.y, w01[j], fmaf(xp1.x, w00[j], b00[j]))));
      *(short8*)&sh1nk[p1n * S_NK + p1hb] = v;
    }
    {
      short8 v;
#pragma unroll
      for (int j = 0; j < 8; j++){
        float x0 = xq[j >> 1][(j & 1) * 2], x1 = xq[j >> 1][(j & 1) * 2 + 1];
        v[j] = (short)f2b(sin_fast(30.f * fmaf(x1, q01, fmaf(x0, q00, qb0))));
      }
      *(short8*)&sh1T[p2h * S_T + p2nb] = v;
    }
    __syncthreads();

    // ---- prefetch pw + x(p1) for nt+1 (completes during phases B+C) ----
    {
      const int nn = (nt + 1 < TS) ? nt + 1 : nt;
      const int n0n = (sseg * TS + nn) * 32;
      short8 pwn[4];
#pragma unroll
      for (int L = 0; L < 4; L++)
        pwn[L] = *(const short8*)(pwsrc + (size_t)L * 524288 + n0n);
      float2 xp1n = *(const float2*)(xbuf + (size_t)(n0n + p1n) * 2);

      // ---- Phase B: h2 GEMM + z0 + z1 + S3 + h2 epilogue -> sh2T ----
      f32x4 h0 = zz, h1a = zz;
#pragma unroll
      for (int ks = 0; ks < 4; ks++){
        h0  = __builtin_amdgcn_mfma_f32_16x16x32_bf16(
                *(short8*)&sh1nk[r16 * S_NK + ks * 32 + quad * 8], w1f[ks], h0, 0, 0, 0);
        h1a = __builtin_amdgcn_mfma_f32_16x16x32_bf16(
                *(short8*)&sh1nk[(16 + r16) * S_NK + ks * 32 + quad * 8], w1f[ks], h1a, 0, 0, 0);
      }
      az0 = __builtin_amdgcn_mfma_f32_16x16x32_bf16(
              *(short8*)&sxT[r16 * S_T + quad * 8], *(short8*)&spw[0][bofs], az0, 0, 0, 0);
#pragma unroll
      for (int mb = 0; mb < 8; mb++)
        az1[mb] = __builtin_amdgcn_mfma_f32_16x16x32_bf16(
                    *(short8*)&sh1T[(mb * 16 + r16) * S_T + quad * 8],
                    *(short8*)&spw[1][bofs], az1[mb], 0, 0, 0);
      az3 = __builtin_amdgcn_mfma_f32_16x16x32_bf16(a1s, *(short8*)&spw[3][bofs], az3, 0, 0, 0);
      {
        short4v v;
#pragma unroll
        for (int r = 0; r < 4; r++) v[r] = (short)f2b(sin_fast(30.f * (h0[r] + bias1)));
        *(short4v*)&sh2T[oo * S_T + quad * 4] = v;
#pragma unroll
        for (int r = 0; r < 4; r++) v[r] = (short)f2b(sin_fast(30.f * (h1a[r] + bias1)));
        *(short4v*)&sh2T[oo * S_T + 16 + quad * 4] = v;
      }
      __syncthreads();

      // ---- Phase C: z2 + y (read sh2T, spw[2], spw[3]) ----
#pragma unroll
      for (int mb = 0; mb < 8; mb++){
        short8 a = *(short8*)&sh2T[(mb * 16 + r16) * S_T + quad * 8];
        az2[mb] = __builtin_amdgcn_mfma_f32_16x16x32_bf16(a, *(short8*)&spw[2][bofs], az2[mb], 0, 0, 0);
        ay[mb]  = __builtin_amdgcn_mfma_f32_16x16x32_bf16(a, *(short8*)&spw[3][bofs], ay[mb], 0, 0, 0);
      }

      // rotate prefetch regs
#pragma unroll
      for (int L = 0; L < 4; L++) pwv[L] = pwn[L];
      xp1 = xp1n;
    }
    __syncthreads();   // protect sh1*/sxT/sh2T/spw for next iteration
  }

  // ---- z3 fold (linear in partials): z3 = W2^T.y + b2*S3 ----
  const int p = oo;
  float S3 = (quad == 0) ? az3[0] : 0.f;
  S3 += __shfl_xor(S3, 16, 64); S3 += __shfl_xor(S3, 32, 64);
  float z3v[3];
#pragma unroll
  for (int d = 0; d < 3; d++){
    float a = 0.f;
#pragma unroll
    for (int mb = 0; mb < 8; mb++)
#pragma unroll
      for (int r = 0; r < 4; r++)
        a = fmaf(sW2[(mb * 16 + quad * 4 + r) * 4 + d], ay[mb][r], a);
    a += __shfl_xor(a, 16, 64); a += __shfl_xor(a, 32, 64);
    z3v[d] = a + sb2[d] * S3;
  }

  if (PARTIAL){
    float* zp = outp + ((size_t)(sseg * 128 + b)) * 261 * 128;
    if (quad == 0){
#pragma unroll
      for (int r = 0; r < 2; r++) zp[(size_t)r * 128 + p] = az0[r];
#pragma unroll
      for (int d = 0; d < 3; d++) zp[(size_t)(258 + d) * 128 + p] = z3v[d];
    }
#pragma unroll
    for (int mb = 0; mb < 8; mb++)
#pragma unroll
      for (int r = 0; r < 4; r++){
        int drow = mb * 16 + quad * 4 + r;
        zp[(size_t)(2 + drow) * 128 + p]   = az1[mb][r];
        zp[(size_t)(130 + drow) * 128 + p] = az2[mb][r];
      }
    return;
  }

  // ---- FULL path: LN stats + emit ----
  const float pb0v = sPB[p],       pb1v = sPB[128 + p];
  const float pb2v = sPB[256 + p], pb3v = sPB[384 + p];

  auto rowsum = [&](float v, int row, bool wr){
    float s1 = sum16(v), s2 = sum16(v * v);
    if (wr && r16 == 0){ sP1[row * 8 + wave] = s1; sP2[row * 8 + wave] = s2; }
  };
#pragma unroll
  for (int r = 0; r < 2; r++) rowsum(az0[r] + pb0v, r, quad == 0);
#pragma unroll
  for (int mb = 0; mb < 8; mb++)
#pragma unroll
    for (int r = 0; r < 4; r++)
      rowsum(az1[mb][r] + pb1v, 2 + mb * 16 + quad * 4 + r, true);
#pragma unroll
  for (int mb = 0; mb < 8; mb++)
#pragma unroll
    for (int r = 0; r < 4; r++)
      rowsum(az2[mb][r] + pb2v, 130 + mb * 16 + quad * 4 + r, true);
#pragma unroll
  for (int d = 0; d < 3; d++) rowsum(z3v[d] + pb3v, 258 + d, quad == 0);
  __syncthreads();

  if (t < 261){
    float s1 = 0.f, s2 = 0.f;
#pragma unroll
    for (int w = 0; w < 8; w++){ s1 += sP1[t * 8 + w]; s2 += sP2[t * 8 + w]; }
    float m = s1 * (1.f / 128.f);
    float var = fmaf(-m, m, s2 * (1.f / 128.f));
    sM[t] = m;
    sI[t] = rsqrtf(fmaxf(var, 0.f) + 1e-5f);
  }
  __syncthreads();

  const size_t ob = (size_t)b * 261 * 128;
  auto emit = [&](float v, int row, int grp){
    outp[ob + (size_t)row * 128 + p] =
      (v - sM[row]) * sI[row] * sG[grp * 128 + p] + sBB[grp * 128 + p];
  };
  if (quad == 0){
#pragma unroll
    for (int r = 0; r < 2; r++) emit(az0[r] + pb0v, r, 0);
#pragma unroll
    for (int d = 0; d < 3; d++) emit(z3v[d] + pb3v, 258 + d, 3);
  }
#pragma unroll
  for (int mb = 0; mb < 8; mb++)
#pragma unroll
    for (int r = 0; r < 4; r++)
      emit(az1[mb][r] + pb1v, 2 + mb * 16 + quad * 4 + r, 1);
#pragma unroll
  for (int mb = 0; mb < 8; mb++)
#pragma unroll
    for (int r = 0; r < 4; r++)
      emit(az2[mb][r] + pb2v, 130 + mb * 16 + quad * 4 + r, 2);
}

// ---------- k_ln: reduce split partials + pb + LayerNorm -> fp32 out ----------
__global__ __launch_bounds__(256)
void k_ln(const float* __restrict__ zp, const void* pbv, const void* lgv,
          const void* lbv, float* __restrict__ out, int split){
  const int bf = is_bf16_fmt(lgv);
  In pb(pbv, bf), lg(lgv, bf), lb(lbv, bf);
  const int lane = threadIdx.x & 63;
  const int row = blockIdx.x * 4 + (threadIdx.x >> 6);   // < 33408
  const int b = row / 261, d = row % 261;
  const int grp = (d < 2) ? 0 : (d < 130) ? 1 : (d < 258) ? 2 : 3;
  const int p0 = lane * 2;
  float v0 = pb.at(grp * 128 + p0), v1 = pb.at(grp * 128 + p0 + 1);
  for (int s2 = 0; s2 < split; s2++){
    const float* zr = zp + ((size_t)(s2 * 128 + b) * 261 + d) * 128;
    v0 += zr[p0]; v1 += zr[p0 + 1];
  }
  float s1 = v0 + v1, s2s = v0 * v0 + v1 * v1;
#pragma unroll
  for (int o = 1; o < 64; o <<= 1){
    s1 += __shfl_xor(s1, o, 64);
    s2s += __shfl_xor(s2s, o, 64);
  }
  float m = s1 * (1.f / 128.f);
  float var = fmaf(-m, m, s2s * (1.f / 128.f));
  float inv = rsqrtf(fmaxf(var, 0.f) + 1e-5f);
  float2 o2;
  o2.x = (v0 - m) * inv * lg.at(grp * 128 + p0)     + lb.at(grp * 128 + p0);
  o2.y = (v1 - m) * inv * lg.at(grp * 128 + p0 + 1) + lb.at(grp * 128 + p0 + 1);
  *(float2*)(out + (size_t)row * 128 + p0) = o2;
}

extern "C" void kernel_launch(void* const* d_in, const int* in_sizes, int n_in,
                              void* d_out, int out_size, void* d_ws, size_t ws_size,
                              hipStream_t stream){
  const void* w0  = d_in[0];
  const void* w1  = d_in[1];
  const void* w2  = d_in[2];
  const void* b0  = d_in[3];
  const void* b1  = d_in[4];
  const void* b2  = d_in[5];
  const void* inp = d_in[6];
  const void* pw  = d_in[7];
  const void* pb  = d_in[8];
  const void* lng = d_in[9];
  const void* lnb = d_in[10];
  float* out = (float*)d_out;

  u16* pwT    = (u16*)d_ws;                                         // 4 MB
  float* xbuf = (float*)((char*)d_ws + (size_t)4 * 128 * 4096 * 2); // 32 KB
  const size_t zoff = (size_t)4 * 128 * 4096 * 2 + 8192 * 4;
  float* zp = (float*)((char*)d_ws + zoff);
  const size_t seg = (size_t)128 * 261 * 128 * 4;                   // 17.1 MB

  const int split = (ws_size >= zoff + 2 * seg) ? 2 : 1;

  k_prep<<<257, 256, 0, stream>>>(pw, inp, lng, pwT, xbuf);
  if (split == 2){
    k_main<true><<<256, 512, 0, stream>>>(w0, w1, w2, b0, b1, b2,
        pb, lng, lnb, pwT, xbuf, zp, 64);
    k_ln<<<(128 * 261) / 4, 256, 0, stream>>>(zp, pb, lng, lnb, out, 2);
  } else {
    k_main<false><<<128, 512, 0, stream>>>(w0, w1, w2, b0, b1, b2,
        pb, lng, lnb, pwT, xbuf, out, 128);
  }
}